// Round 1
// baseline (431.728 us; speedup 1.0000x reference)
//
#include <hip/hip_runtime.h>

#define NB 8
#define NC 192
#define HEADS 6
#define CHH 32
#define IMH 128
#define IMW 128
#define NHW (IMH*IMW)
#define EPSN 1e-12f

// workspace layout (floats)
#define OFF_V   0
#define N_V     (NB*NC*NHW)
#define OFF_QN  (OFF_V + N_V)
#define OFF_KN  (OFF_QN + NB*NC)
#define OFF_ATT (OFF_KN + NB*NC)
#define N_ATT   (NB*HEADS*CHH*CHH)
#define OFF_M   (OFF_ATT + N_ATT)

// K1: fused dwconv(q,k,v) + gram(q·kT) partials + norm partials. v -> ws.
// block = (b, head, 8-row slab); 256 threads.
__global__ __launch_bounds__(256) void k1_conv_attn(
    const float* __restrict__ x,
    const float* __restrict__ wq, const float* __restrict__ bq,
    const float* __restrict__ wk, const float* __restrict__ bk,
    const float* __restrict__ wv, const float* __restrict__ bv,
    float* __restrict__ ws)
{
  __shared__ float q_lds[CHH*129];
  __shared__ float k_lds[CHH*129];
  const int t  = threadIdx.x;
  const int b  = blockIdx.x / HEADS;
  const int h  = blockIdx.x % HEADS;
  const int r0 = blockIdx.y * 8;
  const int c   = t >> 3;      // local channel 0..31 (conv phase)
  const int s   = t & 7;       // 16-px strip
  const int px0 = s * 16;
  const int cg  = h*CHH + c;
  const float* xplane = x + (size_t)(b*NC + cg)*NHW;
  float* vplane = ws + OFF_V + (size_t)(b*NC + cg)*NHW;

  float wqr[9], wkr[9], wvr[9];
#pragma unroll
  for (int m = 0; m < 9; ++m) {
    wqr[m] = wq[cg*9+m]; wkr[m] = wk[cg*9+m]; wvr[m] = wv[cg*9+m];
  }
  const float bqv = bq[cg], bkv = bk[cg], bvv = bv[cg];

  // gram-phase decomposition: 8 x 8 x 4 (tc, td, pp)
  const int tc = t >> 5;
  const int td = (t >> 2) & 7;
  const int pp = t & 3;

  float acc[4][4];
#pragma unroll
  for (int i = 0; i < 4; ++i)
#pragma unroll
    for (int j = 0; j < 4; ++j) acc[i][j] = 0.f;
  float qnacc = 0.f, knacc = 0.f;

  for (int r = r0; r < r0 + 8; ++r) {
    // ---- conv phase: load 3x18 input strip ----
    float xr[3][18];
#pragma unroll
    for (int dr = 0; dr < 3; ++dr) {
      const int rr = r - 1 + dr;
      if (rr >= 0 && rr < IMH) {
        const float* rp = xplane + rr*IMW;
        xr[dr][0] = (px0 > 0) ? rp[px0-1] : 0.f;
#pragma unroll
        for (int q4 = 0; q4 < 4; ++q4) {
          const float4 f = *(const float4*)(rp + px0 + q4*4);
          xr[dr][1+q4*4+0] = f.x; xr[dr][1+q4*4+1] = f.y;
          xr[dr][1+q4*4+2] = f.z; xr[dr][1+q4*4+3] = f.w;
        }
        xr[dr][17] = (px0 + 16 < IMW) ? rp[px0+16] : 0.f;
      } else {
#pragma unroll
        for (int j = 0; j < 18; ++j) xr[dr][j] = 0.f;
      }
    }
    float vbuf[4];
#pragma unroll
    for (int p = 0; p < 16; ++p) {
      float qa = bqv, ka = bkv, va = bvv;
#pragma unroll
      for (int dy = 0; dy < 3; ++dy)
#pragma unroll
        for (int dx = 0; dx < 3; ++dx) {
          const float xv = xr[dy][p+dx];
          qa = fmaf(wqr[dy*3+dx], xv, qa);
          ka = fmaf(wkr[dy*3+dx], xv, ka);
          va = fmaf(wvr[dy*3+dx], xv, va);
        }
      q_lds[c*129 + px0 + p] = qa;
      k_lds[c*129 + px0 + p] = ka;
      qnacc = fmaf(qa, qa, qnacc);
      knacc = fmaf(ka, ka, knacc);
      vbuf[p & 3] = va;
      if ((p & 3) == 3)
        *(float4*)(vplane + r*IMW + px0 + p - 3) =
            make_float4(vbuf[0], vbuf[1], vbuf[2], vbuf[3]);
    }
    __syncthreads();
    // ---- gram phase: acc[i][j] += q[4tc+i][p]*k[4td+j][p], p = pp+4*s2 ----
#pragma unroll 4
    for (int s2 = 0; s2 < 32; ++s2) {
      const int p = pp + 4*s2;
      float qv[4], kv[4];
#pragma unroll
      for (int i = 0; i < 4; ++i) qv[i] = q_lds[(4*tc+i)*129 + p];
#pragma unroll
      for (int j = 0; j < 4; ++j) kv[j] = k_lds[(4*td+j)*129 + p];
#pragma unroll
      for (int i = 0; i < 4; ++i)
#pragma unroll
        for (int j = 0; j < 4; ++j) acc[i][j] = fmaf(qv[i], kv[j], acc[i][j]);
    }
    __syncthreads();
  }

  // ---- norm partials: reduce across 8 strip lanes (contiguous in wave) ----
  qnacc += __shfl_xor(qnacc, 1); qnacc += __shfl_xor(qnacc, 2); qnacc += __shfl_xor(qnacc, 4);
  knacc += __shfl_xor(knacc, 1); knacc += __shfl_xor(knacc, 2); knacc += __shfl_xor(knacc, 4);
  if (s == 0) {
    atomicAdd(ws + OFF_QN + b*NC + cg, qnacc);
    atomicAdd(ws + OFF_KN + b*NC + cg, knacc);
  }

  // ---- gram partials: reduce pp copies via LDS, then atomics ----
  float* red = q_lds;  // reuse (4096 <= 32*129)
  {
    const int base = tc*128 + td*16;
#pragma unroll
    for (int i = 0; i < 4; ++i)
#pragma unroll
      for (int j = 0; j < 4; ++j) red[pp*1024 + base + i*4 + j] = acc[i][j];
  }
  __syncthreads();
  float* attnbuf = ws + OFF_ATT + (b*HEADS + h)*(CHH*CHH);
#pragma unroll
  for (int rep = 0; rep < 4; ++rep) {
    const int idx = rep*256 + t;
    const float sum = red[idx] + red[idx+1024] + red[idx+2048] + red[idx+3072];
    const int tc2 = idx >> 7, td2 = (idx >> 4) & 7, i2 = (idx >> 2) & 3, j2 = idx & 3;
    atomicAdd(attnbuf + (4*tc2+i2)*CHH + (4*td2+j2), sum);
  }
}

// K2: normalize by ||q||,||k||, softmax rows, fold projection:
// MT[b][h*32+d][o] = sum_c' wp[o, h*32+c'] * attn[b,h,c',d]
__global__ __launch_bounds__(256) void k2_softmax_M(
    const float* __restrict__ wp, float* __restrict__ ws)
{
  __shared__ float a[CHH][CHH+1];
  __shared__ float qs[CHH], ks[CHH];
  const int t = threadIdx.x;
  const int b = blockIdx.x / HEADS;
  const int h = blockIdx.x % HEADS;
  const float* raw = ws + OFF_ATT + (b*HEADS + h)*(CHH*CHH);
  if (t < CHH) {
    qs[t] = fmaxf(sqrtf(ws[OFF_QN + b*NC + h*CHH + t]), EPSN);
    ks[t] = fmaxf(sqrtf(ws[OFF_KN + b*NC + h*CHH + t]), EPSN);
  }
  __syncthreads();
#pragma unroll
  for (int rep = 0; rep < 4; ++rep) {
    const int idx = rep*256 + t;
    const int cc = idx >> 5, dd = idx & 31;
    a[cc][dd] = raw[idx] / (qs[cc] * ks[dd]);
  }
  __syncthreads();
  if (t < CHH) {
    float m = -1e30f;
    for (int d = 0; d < CHH; ++d) m = fmaxf(m, a[t][d]);
    float sum = 0.f;
    for (int d = 0; d < CHH; ++d) { const float e = expf(a[t][d] - m); a[t][d] = e; sum += e; }
    const float inv = 1.f / sum;
    for (int d = 0; d < CHH; ++d) a[t][d] *= inv;
  }
  __syncthreads();
  float* MT = ws + OFF_M;
#pragma unroll 2
  for (int rep = 0; rep < 24; ++rep) {
    const int idx = rep*256 + t;
    const int o = idx >> 5, dd = idx & 31;
    float m2 = 0.f;
#pragma unroll
    for (int cp = 0; cp < CHH; ++cp)
      m2 = fmaf(wp[o*NC + h*CHH + cp], a[cp][dd], m2);
    MT[((size_t)b*NC + h*CHH + dd)*NC + o] = m2;
  }
}

// K3: out[b,o,hw] = sum_c MT[b][c][o] * v[b,c,hw] + bp[o]
// block = (64-px tile, b); 4 waves; wave owns 48 wave-uniform outputs (M via s_loads).
__global__ __launch_bounds__(256) void k3_gemm(
    const float* __restrict__ ws, const float* __restrict__ bp,
    float* __restrict__ out)
{
  __shared__ float v_lds[NC*64];
  const int t   = threadIdx.x;
  const int b   = blockIdx.y;
  const int hw0 = blockIdx.x * 64;
  const float* v  = ws + OFF_V;
  const float* MT = ws + OFF_M;
#pragma unroll
  for (int rep = 0; rep < 48; ++rep) {
    const int gi = rep*256 + t;
    const int cc = gi >> 6, p = gi & 63;
    v_lds[gi] = v[(size_t)(b*NC + cc)*NHW + hw0 + p];
  }
  __syncthreads();
  const int lane  = t & 63;
  const int obase = __builtin_amdgcn_readfirstlane((t >> 6) * 48);
  float acc[48];
#pragma unroll
  for (int i = 0; i < 48; ++i) acc[i] = 0.f;
  for (int cc = 0; cc < NC; ++cc) {
    const float vv = v_lds[cc*64 + lane];
    const float* mrow = MT + ((size_t)b*NC + cc)*NC + obase;
#pragma unroll
    for (int i = 0; i < 48; ++i) acc[i] = fmaf(mrow[i], vv, acc[i]);
  }
#pragma unroll
  for (int i = 0; i < 48; ++i) {
    const int o = obase + i;
    out[((size_t)b*NC + o)*NHW + hw0 + lane] = acc[i] + bp[o];
  }
}

extern "C" void kernel_launch(void* const* d_in, const int* in_sizes, int n_in,
                              void* d_out, int out_size, void* d_ws, size_t ws_size,
                              hipStream_t stream)
{
  const float* x  = (const float*)d_in[0];
  const float* wq = (const float*)d_in[1];
  const float* bq = (const float*)d_in[2];
  const float* wk = (const float*)d_in[3];
  const float* bk = (const float*)d_in[4];
  const float* wv = (const float*)d_in[5];
  const float* bv = (const float*)d_in[6];
  const float* wp = (const float*)d_in[7];
  const float* bp = (const float*)d_in[8];
  float* ws  = (float*)d_ws;
  float* out = (float*)d_out;

  // zero the atomic accumulators (qn, kn, attn) — ws is poisoned each call
  hipMemsetAsync(ws + OFF_QN, 0, (size_t)(2*NB*NC + N_ATT)*sizeof(float), stream);

  k1_conv_attn<<<dim3(NB*HEADS, 16), 256, 0, stream>>>(x, wq, bq, wk, bk, wv, bv, ws);
  k2_softmax_M<<<NB*HEADS, 256, 0, stream>>>(wp, ws);
  k3_gemm<<<dim3(NHW/64, NB), 256, 0, stream>>>(ws, bp, out);
}

// Round 2
// 380.509 us; speedup vs baseline: 1.1346x; 1.1346x over previous
//
#include <hip/hip_runtime.h>

#define NB 8
#define NC 192
#define HEADS 6
#define CHH 32
#define IMH 128
#define IMW 128
#define NHW (IMH*IMW)
#define EPSN 1e-12f
#define NBCHW (NB*NC*NHW)   // 25165824 elements

typedef __attribute__((ext_vector_type(8))) short short8_t;   // bf16x8 MFMA operand
typedef __attribute__((ext_vector_type(4))) float floatx4;    // MFMA C/D frag
typedef unsigned short ushort_t;

#define MFMA_B16(a,b,c) __builtin_amdgcn_mfma_f32_16x16x32_bf16(a,b,c,0,0,0)

__device__ __forceinline__ ushort_t f2bf(float v){
  union { float f; unsigned u; } x; x.f = v;
  unsigned r = x.u + 0x7fffu + ((x.u >> 16) & 1u);   // RNE
  return (ushort_t)(r >> 16);
}
__device__ __forceinline__ float bf2f(ushort_t h){
  union { unsigned u; float f; } x; x.u = ((unsigned)h) << 16;
  return x.f;
}
__device__ __forceinline__ void split8(const float* f, short8_t& hi, short8_t& lo){
#pragma unroll
  for (int i = 0; i < 8; ++i) {
    ushort_t h = f2bf(f[i]);
    hi[i] = (short)h;
    lo[i] = (short)f2bf(f[i] - bf2f(h));
  }
}

// ---------------------------------------------------------------------------
// K1: dwconv(q,k,v) fused with MFMA gram partials + norm partials.
// V is transposed through LDS and stored [b][hw][c] as bf16 hi/lo planes.
// block = (b,head) x 8-row slab, 256 threads (4 waves).
// ---------------------------------------------------------------------------
__global__ __launch_bounds__(256) void k1_conv_gram(
    const float* __restrict__ x,
    const float* __restrict__ wq, const float* __restrict__ bq,
    const float* __restrict__ wk, const float* __restrict__ bk,
    const float* __restrict__ wv, const float* __restrict__ bv,
    ushort_t* __restrict__ vhi, ushort_t* __restrict__ vlo,
    float* __restrict__ qn, float* __restrict__ kn,
    float* __restrict__ attn)
{
  __shared__ float qls[CHH*132];   // fp32 [c][132]
  __shared__ float kls[CHH*132];
  __shared__ float vls[CHH*132];
  const int t  = threadIdx.x;
  const int b  = blockIdx.x / HEADS;
  const int h  = blockIdx.x % HEADS;
  const int r0 = blockIdx.y * 8;
  const int c   = t >> 3;        // conv channel 0..31
  const int s   = t & 7;         // 16-px strip
  const int px0 = s * 16;
  const int cg  = h*CHH + c;
  const float* xplane = x + (size_t)(b*NC + cg)*NHW;

  float wqr[9], wkr[9], wvr[9];
#pragma unroll
  for (int m = 0; m < 9; ++m) {
    wqr[m] = wq[cg*9+m]; wkr[m] = wk[cg*9+m]; wvr[m] = wv[cg*9+m];
  }
  const float bqv = bq[cg], bkv = bk[cg], bvv = bv[cg];

  // gram wave decomposition
  const int lane  = t & 63;
  const int wid   = t >> 6;             // wave 0..3 -> 32-px slice
  const int pw    = wid * 32;
  const int gsel  = lane >> 4;          // k-group 0..3
  const int arow0 = (lane & 15)*132 + pw + gsel*8;

  floatx4 acc[2][2];
#pragma unroll
  for (int mt = 0; mt < 2; ++mt)
#pragma unroll
    for (int nt = 0; nt < 2; ++nt) acc[mt][nt] = (floatx4){0.f,0.f,0.f,0.f};
  float qnacc = 0.f, knacc = 0.f;

  for (int r = r0; r < r0 + 8; ++r) {
    // ---- conv phase ----
    float xr[3][18];
#pragma unroll
    for (int dr = 0; dr < 3; ++dr) {
      const int rr = r - 1 + dr;
      if (rr >= 0 && rr < IMH) {
        const float* rp = xplane + rr*IMW;
        xr[dr][0] = (px0 > 0) ? rp[px0-1] : 0.f;
#pragma unroll
        for (int q4 = 0; q4 < 4; ++q4) {
          const float4 fv = *(const float4*)(rp + px0 + q4*4);
          xr[dr][1+q4*4+0] = fv.x; xr[dr][1+q4*4+1] = fv.y;
          xr[dr][1+q4*4+2] = fv.z; xr[dr][1+q4*4+3] = fv.w;
        }
        xr[dr][17] = (px0 + 16 < IMW) ? rp[px0+16] : 0.f;
      } else {
#pragma unroll
        for (int j = 0; j < 18; ++j) xr[dr][j] = 0.f;
      }
    }
    float qst[4], kst[4], vst[4];
#pragma unroll
    for (int p = 0; p < 16; ++p) {
      float qa = bqv, ka = bkv, va = bvv;
#pragma unroll
      for (int dy = 0; dy < 3; ++dy)
#pragma unroll
        for (int dx = 0; dx < 3; ++dx) {
          const float xv = xr[dy][p+dx];
          qa = fmaf(wqr[dy*3+dx], xv, qa);
          ka = fmaf(wkr[dy*3+dx], xv, ka);
          va = fmaf(wvr[dy*3+dx], xv, va);
        }
      qnacc = fmaf(qa, qa, qnacc);
      knacc = fmaf(ka, ka, knacc);
      qst[p&3] = qa; kst[p&3] = ka; vst[p&3] = va;
      if ((p&3) == 3) {
        *(float4*)&qls[c*132 + px0 + p - 3] = make_float4(qst[0],qst[1],qst[2],qst[3]);
        *(float4*)&kls[c*132 + px0 + p - 3] = make_float4(kst[0],kst[1],kst[2],kst[3]);
        *(float4*)&vls[c*132 + px0 + p - 3] = make_float4(vst[0],vst[1],vst[2],vst[3]);
      }
    }
    __syncthreads();

    // ---- gram phase: 3-product bf16-split MFMA (K = 32 px of this wave) ----
    {
      short8_t qh[2], qlo[2], kh[2], klo[2];
#pragma unroll
      for (int mt = 0; mt < 2; ++mt) {
        float fa[8];
        const float* pq = &qls[mt*16*132 + arow0];
        float4 a0 = *(const float4*)pq; float4 a1 = *(const float4*)(pq+4);
        fa[0]=a0.x; fa[1]=a0.y; fa[2]=a0.z; fa[3]=a0.w;
        fa[4]=a1.x; fa[5]=a1.y; fa[6]=a1.z; fa[7]=a1.w;
        split8(fa, qh[mt], qlo[mt]);
        const float* pk = &kls[mt*16*132 + arow0];
        float4 b0 = *(const float4*)pk; float4 b1 = *(const float4*)(pk+4);
        fa[0]=b0.x; fa[1]=b0.y; fa[2]=b0.z; fa[3]=b0.w;
        fa[4]=b1.x; fa[5]=b1.y; fa[6]=b1.z; fa[7]=b1.w;
        split8(fa, kh[mt], klo[mt]);
      }
#pragma unroll
      for (int mt = 0; mt < 2; ++mt)
#pragma unroll
        for (int nt = 0; nt < 2; ++nt) {
          acc[mt][nt] = MFMA_B16(qh[mt],  kh[nt],  acc[mt][nt]);
          acc[mt][nt] = MFMA_B16(qh[mt],  klo[nt], acc[mt][nt]);
          acc[mt][nt] = MFMA_B16(qlo[mt], kh[nt],  acc[mt][nt]);
        }
    }

    // ---- v transpose -> global [hw][c] bf16 hi/lo ----
#pragma unroll
    for (int cc2 = 0; cc2 < 2; ++cc2) {
      const int id  = cc2*256 + t;
      const int oct = id & 3;          // 8-channel octet
      const int px  = id >> 2;         // 0..127
      float f[8];
#pragma unroll
      for (int i = 0; i < 8; ++i) f[i] = vls[(oct*8+i)*132 + px];
      unsigned uh[4], ul[4];
#pragma unroll
      for (int j = 0; j < 4; ++j) {
        ushort_t h0 = f2bf(f[2*j]),   h1 = f2bf(f[2*j+1]);
        ushort_t l0 = f2bf(f[2*j]   - bf2f(h0));
        ushort_t l1 = f2bf(f[2*j+1] - bf2f(h1));
        uh[j] = (unsigned)h0 | ((unsigned)h1 << 16);
        ul[j] = (unsigned)l0 | ((unsigned)l1 << 16);
      }
      const size_t gbase = ((size_t)b*NHW + (size_t)r*IMW + px)*NC + h*CHH + oct*8;
      *(uint4*)(vhi + gbase) = make_uint4(uh[0],uh[1],uh[2],uh[3]);
      *(uint4*)(vlo + gbase) = make_uint4(ul[0],ul[1],ul[2],ul[3]);
    }
    __syncthreads();
  }

  // ---- norm partials ----
  qnacc += __shfl_xor(qnacc, 1); qnacc += __shfl_xor(qnacc, 2); qnacc += __shfl_xor(qnacc, 4);
  knacc += __shfl_xor(knacc, 1); knacc += __shfl_xor(knacc, 2); knacc += __shfl_xor(knacc, 4);
  if (s == 0) {
    atomicAdd(qn + b*NC + cg, qnacc);
    atomicAdd(kn + b*NC + cg, knacc);
  }

  // ---- gram partials: 4-wave LDS reduce, then atomics ----
  float* red = qls;   // 4096 <= 32*132
#pragma unroll
  for (int mt = 0; mt < 2; ++mt)
#pragma unroll
    for (int nt = 0; nt < 2; ++nt)
#pragma unroll
      for (int rg = 0; rg < 4; ++rg)
        red[wid*1024 + (mt*2+nt)*256 + lane*4 + rg] = acc[mt][nt][rg];
  __syncthreads();
  float* abuf = attn + (b*HEADS + h)*(CHH*CHH);
#pragma unroll
  for (int e = 0; e < 4; ++e) {
    const int idx = e*256 + t;
    const float sum = red[idx] + red[1024+idx] + red[2048+idx] + red[3072+idx];
    const int tile = idx >> 8;
    const int ln   = (idx >> 2) & 63;
    const int rg   = idx & 3;
    const int cc   = (tile>>1)*16 + (ln>>4)*4 + rg;
    const int dd   = (tile&1)*16 + (ln & 15);
    atomicAdd(abuf + cc*CHH + dd, sum);
  }
}

// ---------------------------------------------------------------------------
// K2: normalize, softmax rows, fold projection: M[b][o][h*32+d] (bf16 hi/lo)
// ---------------------------------------------------------------------------
__global__ __launch_bounds__(256) void k2_softmax_M(
    const float* __restrict__ wp,
    const float* __restrict__ qn, const float* __restrict__ kn,
    const float* __restrict__ attn,
    ushort_t* __restrict__ mhi, ushort_t* __restrict__ mlo)
{
  __shared__ float a[CHH][CHH+1];
  __shared__ float qs[CHH], ks[CHH];
  const int t = threadIdx.x;
  const int b = blockIdx.x / HEADS;
  const int h = blockIdx.x % HEADS;
  const float* raw = attn + (b*HEADS + h)*(CHH*CHH);
  if (t < CHH) {
    qs[t] = fmaxf(sqrtf(qn[b*NC + h*CHH + t]), EPSN);
    ks[t] = fmaxf(sqrtf(kn[b*NC + h*CHH + t]), EPSN);
  }
  __syncthreads();
#pragma unroll
  for (int rep = 0; rep < 4; ++rep) {
    const int idx = rep*256 + t;
    const int cc = idx >> 5, dd = idx & 31;
    a[cc][dd] = raw[idx] / (qs[cc] * ks[dd]);
  }
  __syncthreads();
  if (t < CHH) {
    float m = -1e30f;
    for (int d = 0; d < CHH; ++d) m = fmaxf(m, a[t][d]);
    float sum = 0.f;
    for (int d = 0; d < CHH; ++d) { const float e = expf(a[t][d] - m); a[t][d] = e; sum += e; }
    const float inv = 1.f / sum;
    for (int d = 0; d < CHH; ++d) a[t][d] *= inv;
  }
  __syncthreads();
#pragma unroll 4
  for (int rep = 0; rep < 24; ++rep) {
    const int idx = rep*256 + t;
    const int o = idx >> 5, dd = idx & 31;
    float m = 0.f;
#pragma unroll
    for (int cp = 0; cp < CHH; ++cp)
      m = fmaf(wp[o*NC + h*CHH + cp], a[cp][dd], m);
    const ushort_t hi_ = f2bf(m);
    const ushort_t lo_ = f2bf(m - bf2f(hi_));
    const size_t mi = ((size_t)b*NC + o)*NC + h*CHH + dd;
    mhi[mi] = hi_; mlo[mi] = lo_;
  }
}

// ---------------------------------------------------------------------------
// K3: out[b,o,hw] = sum_c M[b,o,c]*V[b,hw,c] + bp[o]  (bf16-split MFMA, no LDS)
// block: 64 hw x all 192 o; wave (wo,wh) owns 96 o x 32 hw.
// ---------------------------------------------------------------------------
__global__ __launch_bounds__(256) void k3_gemm(
    const ushort_t* __restrict__ vhi, const ushort_t* __restrict__ vlo,
    const ushort_t* __restrict__ mhi, const ushort_t* __restrict__ mlo,
    const float* __restrict__ bp, float* __restrict__ out)
{
  const int t    = threadIdx.x;
  const int b    = blockIdx.y;
  const int hw0  = blockIdx.x * 64;
  const int lane = t & 63;
  const int w    = t >> 6;
  const int wo   = w >> 1, wh = w & 1;
  const int obase = wo * 96;
  const int hwb   = hw0 + wh * 32;
  const int gsel  = lane >> 4;
  const int l15   = lane & 15;

  floatx4 acc[6][2];
#pragma unroll
  for (int ot = 0; ot < 6; ++ot)
#pragma unroll
    for (int nt = 0; nt < 2; ++nt) acc[ot][nt] = (floatx4){0.f,0.f,0.f,0.f};

#pragma unroll 2
  for (int ks = 0; ks < 6; ++ks) {
    const int c0 = ks*32 + gsel*8;
    short8_t bh[2], bl[2];
#pragma unroll
    for (int nt = 0; nt < 2; ++nt) {
      const size_t va = ((size_t)b*NHW + hwb + nt*16 + l15)*NC + c0;
      bh[nt] = *(const short8_t*)(vhi + va);
      bl[nt] = *(const short8_t*)(vlo + va);
    }
#pragma unroll
    for (int ot = 0; ot < 6; ++ot) {
      const size_t ma = ((size_t)b*NC + obase + ot*16 + l15)*NC + c0;
      const short8_t ah = *(const short8_t*)(mhi + ma);
      const short8_t al = *(const short8_t*)(mlo + ma);
#pragma unroll
      for (int nt = 0; nt < 2; ++nt) {
        acc[ot][nt] = MFMA_B16(ah, bh[nt], acc[ot][nt]);
        acc[ot][nt] = MFMA_B16(ah, bl[nt], acc[ot][nt]);
        acc[ot][nt] = MFMA_B16(al, bh[nt], acc[ot][nt]);
      }
    }
  }
#pragma unroll
  for (int ot = 0; ot < 6; ++ot) {
#pragma unroll
    for (int rg = 0; rg < 4; ++rg) {
      const int o = obase + ot*16 + gsel*4 + rg;
      const float bpv = bp[o];
#pragma unroll
      for (int nt = 0; nt < 2; ++nt) {
        const int hw = hwb + nt*16 + l15;
        out[((size_t)(b*NC + o))*NHW + hw] = acc[ot][nt][rg] + bpv;
      }
    }
  }
}

extern "C" void kernel_launch(void* const* d_in, const int* in_sizes, int n_in,
                              void* d_out, int out_size, void* d_ws, size_t ws_size,
                              hipStream_t stream)
{
  const float* x  = (const float*)d_in[0];
  const float* wq = (const float*)d_in[1];
  const float* bq = (const float*)d_in[2];
  const float* wk = (const float*)d_in[3];
  const float* bk = (const float*)d_in[4];
  const float* wv = (const float*)d_in[5];
  const float* bv = (const float*)d_in[6];
  const float* wp = (const float*)d_in[7];
  const float* bp = (const float*)d_in[8];
  float* out = (float*)d_out;

  // workspace layout
  ushort_t* vhi = (ushort_t*)d_ws;
  ushort_t* vlo = vhi + (size_t)NBCHW;
  float* fbase  = (float*)(vlo + (size_t)NBCHW);
  float* qn     = fbase;
  float* kn     = qn + NB*NC;
  float* attn   = kn + NB*NC;
  ushort_t* mhi = (ushort_t*)(attn + NB*HEADS*CHH*CHH);
  ushort_t* mlo = mhi + (size_t)NB*NC*NC;

  hipMemsetAsync(fbase, 0,
                 (size_t)(2*NB*NC + NB*HEADS*CHH*CHH)*sizeof(float), stream);

  k1_conv_gram<<<dim3(NB*HEADS, 16), 256, 0, stream>>>(
      x, wq, bq, wk, bk, wv, bv, vhi, vlo, qn, kn, attn);
  k2_softmax_M<<<NB*HEADS, 256, 0, stream>>>(wp, qn, kn, attn, mhi, mlo);
  k3_gemm<<<dim3(NHW/64, NB), 256, 0, stream>>>(vhi, vlo, mhi, mlo, bp, out);
}

// Round 3
// 282.170 us; speedup vs baseline: 1.5300x; 1.3485x over previous
//
#include <hip/hip_runtime.h>

#define NB 8
#define NC 192
#define HEADS 6
#define CHH 32
#define IMH 128
#define IMW 128
#define NHW (IMH*IMW)
#define EPSN 1e-12f
#define NBCHW (NB*NC*NHW)   // 25165824 elements

typedef __attribute__((ext_vector_type(8))) short short8_t;   // bf16x8 MFMA operand
typedef __attribute__((ext_vector_type(4))) float floatx4;    // MFMA C/D frag
typedef unsigned short ushort_t;

#define MFMA_B16(a,b,c) __builtin_amdgcn_mfma_f32_16x16x32_bf16(a,b,c,0,0,0)

__device__ __forceinline__ ushort_t f2bf(float v){
  union { float f; unsigned u; } x; x.f = v;
  unsigned r = x.u + 0x7fffu + ((x.u >> 16) & 1u);   // RNE
  return (ushort_t)(r >> 16);
}
__device__ __forceinline__ float bf2f(ushort_t h){
  union { unsigned u; float f; } x; x.u = ((unsigned)h) << 16;
  return x.f;
}
__device__ __forceinline__ void split8(const float* f, short8_t& hi, short8_t& lo){
#pragma unroll
  for (int i = 0; i < 8; ++i) {
    ushort_t h = f2bf(f[i]);
    hi[i] = (short)h;
    lo[i] = (short)f2bf(f[i] - bf2f(h));
  }
}

// ---------------------------------------------------------------------------
// K1: dwconv(q,k,v) fused with MFMA gram partials + norm partials.
// V is transposed through LDS and stored PRE-PACKED in k3's MFMA B-frag tile
// order: plane[((b*1024 + ht)*6 + ks)*64 + lane] (short8 per lane).
// block = (b,head) x 8-row slab, 256 threads (4 waves).
// ---------------------------------------------------------------------------
__global__ __launch_bounds__(256) void k1_conv_gram(
    const float* __restrict__ x,
    const float* __restrict__ wq, const float* __restrict__ bq,
    const float* __restrict__ wk, const float* __restrict__ bk,
    const float* __restrict__ wv, const float* __restrict__ bv,
    ushort_t* __restrict__ vhi, ushort_t* __restrict__ vlo,
    float* __restrict__ qn, float* __restrict__ kn,
    float* __restrict__ attn)
{
  __shared__ float qls[CHH*132];   // fp32 [c][132]
  __shared__ float kls[CHH*132];
  __shared__ float vls[CHH*132];
  const int t  = threadIdx.x;
  const int b  = blockIdx.x / HEADS;
  const int h  = blockIdx.x % HEADS;
  const int r0 = blockIdx.y * 8;
  const int c   = t >> 3;        // conv channel 0..31
  const int s   = t & 7;         // 16-px strip
  const int px0 = s * 16;
  const int cg  = h*CHH + c;
  const float* xplane = x + (size_t)(b*NC + cg)*NHW;

  float wqr[9], wkr[9], wvr[9];
#pragma unroll
  for (int m = 0; m < 9; ++m) {
    wqr[m] = wq[cg*9+m]; wkr[m] = wk[cg*9+m]; wvr[m] = wv[cg*9+m];
  }
  const float bqv = bq[cg], bkv = bk[cg], bvv = bv[cg];

  // gram wave decomposition
  const int lane  = t & 63;
  const int wid   = t >> 6;             // wave 0..3 -> 32-px slice
  const int pw    = wid * 32;
  const int gsel  = lane >> 4;          // k-group 0..3
  const int arow0 = (lane & 15)*132 + pw + gsel*8;

  floatx4 acc[2][2];
#pragma unroll
  for (int mt = 0; mt < 2; ++mt)
#pragma unroll
    for (int nt = 0; nt < 2; ++nt) acc[mt][nt] = (floatx4){0.f,0.f,0.f,0.f};
  float qnacc = 0.f, knacc = 0.f;

  for (int r = r0; r < r0 + 8; ++r) {
    // ---- conv phase ----
    float xr[3][18];
#pragma unroll
    for (int dr = 0; dr < 3; ++dr) {
      const int rr = r - 1 + dr;
      if (rr >= 0 && rr < IMH) {
        const float* rp = xplane + rr*IMW;
        xr[dr][0] = (px0 > 0) ? rp[px0-1] : 0.f;
#pragma unroll
        for (int q4 = 0; q4 < 4; ++q4) {
          const float4 fv = *(const float4*)(rp + px0 + q4*4);
          xr[dr][1+q4*4+0] = fv.x; xr[dr][1+q4*4+1] = fv.y;
          xr[dr][1+q4*4+2] = fv.z; xr[dr][1+q4*4+3] = fv.w;
        }
        xr[dr][17] = (px0 + 16 < IMW) ? rp[px0+16] : 0.f;
      } else {
#pragma unroll
        for (int j = 0; j < 18; ++j) xr[dr][j] = 0.f;
      }
    }
    float qst[4], kst[4], vst[4];
#pragma unroll
    for (int p = 0; p < 16; ++p) {
      float qa = bqv, ka = bkv, va = bvv;
#pragma unroll
      for (int dy = 0; dy < 3; ++dy)
#pragma unroll
        for (int dx = 0; dx < 3; ++dx) {
          const float xv = xr[dy][p+dx];
          qa = fmaf(wqr[dy*3+dx], xv, qa);
          ka = fmaf(wkr[dy*3+dx], xv, ka);
          va = fmaf(wvr[dy*3+dx], xv, va);
        }
      qnacc = fmaf(qa, qa, qnacc);
      knacc = fmaf(ka, ka, knacc);
      qst[p&3] = qa; kst[p&3] = ka; vst[p&3] = va;
      if ((p&3) == 3) {
        *(float4*)&qls[c*132 + px0 + p - 3] = make_float4(qst[0],qst[1],qst[2],qst[3]);
        *(float4*)&kls[c*132 + px0 + p - 3] = make_float4(kst[0],kst[1],kst[2],kst[3]);
        *(float4*)&vls[c*132 + px0 + p - 3] = make_float4(vst[0],vst[1],vst[2],vst[3]);
      }
    }
    __syncthreads();

    // ---- gram phase: 3-product bf16-split MFMA (K = 32 px of this wave) ----
    {
      short8_t qh[2], qlo[2], kh[2], klo[2];
#pragma unroll
      for (int mt = 0; mt < 2; ++mt) {
        float fa[8];
        const float* pq = &qls[mt*16*132 + arow0];
        float4 a0 = *(const float4*)pq; float4 a1 = *(const float4*)(pq+4);
        fa[0]=a0.x; fa[1]=a0.y; fa[2]=a0.z; fa[3]=a0.w;
        fa[4]=a1.x; fa[5]=a1.y; fa[6]=a1.z; fa[7]=a1.w;
        split8(fa, qh[mt], qlo[mt]);
        const float* pk = &kls[mt*16*132 + arow0];
        float4 b0 = *(const float4*)pk; float4 b1 = *(const float4*)(pk+4);
        fa[0]=b0.x; fa[1]=b0.y; fa[2]=b0.z; fa[3]=b0.w;
        fa[4]=b1.x; fa[5]=b1.y; fa[6]=b1.z; fa[7]=b1.w;
        split8(fa, kh[mt], klo[mt]);
      }
#pragma unroll
      for (int mt = 0; mt < 2; ++mt)
#pragma unroll
        for (int nt = 0; nt < 2; ++nt) {
          acc[mt][nt] = MFMA_B16(qh[mt],  kh[nt],  acc[mt][nt]);
          acc[mt][nt] = MFMA_B16(qh[mt],  klo[nt], acc[mt][nt]);
          acc[mt][nt] = MFMA_B16(qlo[mt], kh[nt],  acc[mt][nt]);
        }
    }

    // ---- v transpose -> global, PRE-PACKED k3 B-frag layout ----
#pragma unroll
    for (int cc2 = 0; cc2 < 2; ++cc2) {
      const int id  = cc2*256 + t;
      const int oct = id & 3;          // 8-channel octet == frag gsel
      const int px  = id >> 2;         // 0..127
      float f[8];
#pragma unroll
      for (int i = 0; i < 8; ++i) f[i] = vls[(oct*8+i)*132 + px];
      unsigned uh[4], ul[4];
#pragma unroll
      for (int j = 0; j < 4; ++j) {
        ushort_t h0 = f2bf(f[2*j]),   h1 = f2bf(f[2*j+1]);
        ushort_t l0 = f2bf(f[2*j]   - bf2f(h0));
        ushort_t l1 = f2bf(f[2*j+1] - bf2f(h1));
        uh[j] = (unsigned)h0 | ((unsigned)h1 << 16);
        ul[j] = (unsigned)l0 | ((unsigned)l1 << 16);
      }
      // frag tile: ht = r*8 + px/16 ; ks = h ; lane = oct*16 + (px&15)
      const size_t tile  = ((size_t)b*1024 + (size_t)r*8 + (px>>4))*6 + h;
      const size_t gbase = (tile*64 + (size_t)(oct*16 + (px&15))) * 8;
      *(uint4*)(vhi + gbase) = make_uint4(uh[0],uh[1],uh[2],uh[3]);
      *(uint4*)(vlo + gbase) = make_uint4(ul[0],ul[1],ul[2],ul[3]);
    }
    __syncthreads();
  }

  // ---- norm partials ----
  qnacc += __shfl_xor(qnacc, 1); qnacc += __shfl_xor(qnacc, 2); qnacc += __shfl_xor(qnacc, 4);
  knacc += __shfl_xor(knacc, 1); knacc += __shfl_xor(knacc, 2); knacc += __shfl_xor(knacc, 4);
  if (s == 0) {
    atomicAdd(qn + b*NC + cg, qnacc);
    atomicAdd(kn + b*NC + cg, knacc);
  }

  // ---- gram partials: 4-wave LDS reduce, then atomics ----
  float* red = qls;   // 4096 <= 32*132
#pragma unroll
  for (int mt = 0; mt < 2; ++mt)
#pragma unroll
    for (int nt = 0; nt < 2; ++nt)
#pragma unroll
      for (int rg = 0; rg < 4; ++rg)
        red[wid*1024 + (mt*2+nt)*256 + lane*4 + rg] = acc[mt][nt][rg];
  __syncthreads();
  float* abuf = attn + (b*HEADS + h)*(CHH*CHH);
#pragma unroll
  for (int e = 0; e < 4; ++e) {
    const int idx = e*256 + t;
    const float sum = red[idx] + red[1024+idx] + red[2048+idx] + red[3072+idx];
    const int tile = idx >> 8;
    const int ln   = (idx >> 2) & 63;
    const int rg   = idx & 3;
    const int cc   = (tile>>1)*16 + (ln>>4)*4 + rg;
    const int dd   = (tile&1)*16 + (ln & 15);
    atomicAdd(abuf + cc*CHH + dd, sum);
  }
}

// ---------------------------------------------------------------------------
// K2: normalize, softmax rows, fold projection; M written PRE-PACKED in k3's
// MFMA A-frag tile order: plane[((b*12 + ot)*6 + ks)*64 + lane] (short8).
// ---------------------------------------------------------------------------
__global__ __launch_bounds__(256) void k2_softmax_M(
    const float* __restrict__ wp,
    const float* __restrict__ qn, const float* __restrict__ kn,
    const float* __restrict__ attn,
    short8_t* __restrict__ mhi, short8_t* __restrict__ mlo)
{
  __shared__ float a[CHH][CHH+1];
  __shared__ float qs[CHH], ks_[CHH];
  const int t = threadIdx.x;
  const int b = blockIdx.x / HEADS;
  const int h = blockIdx.x % HEADS;
  const float* raw = attn + (b*HEADS + h)*(CHH*CHH);
  if (t < CHH) {
    qs[t]  = fmaxf(sqrtf(qn[b*NC + h*CHH + t]), EPSN);
    ks_[t] = fmaxf(sqrtf(kn[b*NC + h*CHH + t]), EPSN);
  }
  __syncthreads();
#pragma unroll
  for (int rep = 0; rep < 4; ++rep) {
    const int idx = rep*256 + t;
    const int cc = idx >> 5, dd = idx & 31;
    a[cc][dd] = raw[idx] / (qs[cc] * ks_[dd]);
  }
  __syncthreads();
  if (t < CHH) {
    float m = -1e30f;
    for (int d = 0; d < CHH; ++d) m = fmaxf(m, a[t][d]);
    float sum = 0.f;
    for (int d = 0; d < CHH; ++d) { const float e = expf(a[t][d] - m); a[t][d] = e; sum += e; }
    const float inv = 1.f / sum;
    for (int d = 0; d < CHH; ++d) a[t][d] *= inv;
  }
  __syncthreads();
  // each slot = one (o, dd-octet): 192*4 = 768 slots
#pragma unroll
  for (int rep = 0; rep < 3; ++rep) {
    const int slot = rep*256 + t;
    const int o = slot >> 2;
    const int g = slot & 3;
    float m[8];
#pragma unroll
    for (int i = 0; i < 8; ++i) m[i] = 0.f;
    for (int cp = 0; cp < CHH; ++cp) {
      const float w = wp[o*NC + h*CHH + cp];
#pragma unroll
      for (int i = 0; i < 8; ++i) m[i] = fmaf(w, a[cp][g*8+i], m[i]);
    }
    short8_t hi, lo;
    split8(m, hi, lo);
    const size_t mi = (((size_t)b*12 + (o>>4))*6 + h)*64 + g*16 + (o&15);
    mhi[mi] = hi; mlo[mi] = lo;
  }
}

// ---------------------------------------------------------------------------
// K3: out[b,o,hw] = sum_c M[b,o,c]*V[b,hw,c] + bp[o]  (bf16-split MFMA)
// Both operands pre-packed in frag tile order -> every load = base + lane*16B.
// block = 128 px x 192 o, 4 waves; wave = 64 px (4 tiles) x 96 o (6 tiles).
// ---------------------------------------------------------------------------
__global__ __launch_bounds__(256) void k3_gemm(
    const short8_t* __restrict__ vhi, const short8_t* __restrict__ vlo,
    const short8_t* __restrict__ mhi, const short8_t* __restrict__ mlo,
    const float* __restrict__ bp, float* __restrict__ out)
{
  const int t    = threadIdx.x;
  const int b    = blockIdx.y;
  const int lane = t & 63;
  const int w    = t >> 6;
  const int whw  = w & 1;                 // hw half of block
  const int wo   = w >> 1;                // o half of block
  const int ht0  = blockIdx.x*8 + whw*4;  // first of 4 hw-tiles
  const int ot0  = wo*6;                  // first of 6 o-tiles
  const int gsel = lane >> 4, l15 = lane & 15;

  floatx4 acc[6][4];
#pragma unroll
  for (int ot = 0; ot < 6; ++ot)
#pragma unroll
    for (int nt = 0; nt < 4; ++nt) acc[ot][nt] = (floatx4){0.f,0.f,0.f,0.f};

  const size_t vbase = ((size_t)b*1024 + ht0)*6;
  const size_t mbase = ((size_t)b*12 + ot0)*6;
#pragma unroll 2
  for (int ks = 0; ks < 6; ++ks) {
    short8_t bh[4], bl[4];
#pragma unroll
    for (int nt = 0; nt < 4; ++nt) {
      const size_t vi = (vbase + (size_t)nt*6 + ks)*64 + lane;
      bh[nt] = vhi[vi]; bl[nt] = vlo[vi];
    }
#pragma unroll
    for (int ot = 0; ot < 6; ++ot) {
      const size_t mi = (mbase + (size_t)ot*6 + ks)*64 + lane;
      const short8_t ah = mhi[mi];
      const short8_t al = mlo[mi];
#pragma unroll
      for (int nt = 0; nt < 4; ++nt) {
        acc[ot][nt] = MFMA_B16(ah, bh[nt], acc[ot][nt]);
        acc[ot][nt] = MFMA_B16(ah, bl[nt], acc[ot][nt]);
        acc[ot][nt] = MFMA_B16(al, bh[nt], acc[ot][nt]);
      }
    }
  }
#pragma unroll
  for (int ot = 0; ot < 6; ++ot) {
#pragma unroll
    for (int rg = 0; rg < 4; ++rg) {
      const int o = (ot0 + ot)*16 + gsel*4 + rg;
      const float bpv = bp[o];
#pragma unroll
      for (int nt = 0; nt < 4; ++nt) {
        const int hw = (ht0 + nt)*16 + l15;
        out[((size_t)(b*NC + o))*NHW + hw] = acc[ot][nt][rg] + bpv;
      }
    }
  }
}

extern "C" void kernel_launch(void* const* d_in, const int* in_sizes, int n_in,
                              void* d_out, int out_size, void* d_ws, size_t ws_size,
                              hipStream_t stream)
{
  const float* x  = (const float*)d_in[0];
  const float* wq = (const float*)d_in[1];
  const float* bq = (const float*)d_in[2];
  const float* wk = (const float*)d_in[3];
  const float* bk = (const float*)d_in[4];
  const float* wv = (const float*)d_in[5];
  const float* bv = (const float*)d_in[6];
  const float* wp = (const float*)d_in[7];
  const float* bp = (const float*)d_in[8];
  float* out = (float*)d_out;

  // workspace layout
  ushort_t* vhi = (ushort_t*)d_ws;
  ushort_t* vlo = vhi + (size_t)NBCHW;
  float* fbase  = (float*)(vlo + (size_t)NBCHW);
  float* qn     = fbase;
  float* kn     = qn + NB*NC;
  float* attn   = kn + NB*NC;
  short8_t* mhi = (short8_t*)(attn + NB*HEADS*CHH*CHH);
  short8_t* mlo = mhi + (size_t)NB*12*6*64;

  hipMemsetAsync(fbase, 0,
                 (size_t)(2*NB*NC + NB*HEADS*CHH*CHH)*sizeof(float), stream);

  k1_conv_gram<<<dim3(NB*HEADS, 16), 256, 0, stream>>>(
      x, wq, bq, wk, bk, wv, bv, vhi, vlo, qn, kn, attn);
  k2_softmax_M<<<NB*HEADS, 256, 0, stream>>>(wp, qn, kn, attn, mhi, mlo);
  k3_gemm<<<dim3(NHW/128, NB), 256, 0, stream>>>(
      (const short8_t*)vhi, (const short8_t*)vlo, mhi, mlo, bp, out);
}